// Round 8
// baseline (564.128 us; speedup 1.0000x reference)
//
#include <hip/hip_runtime.h>

#define RD 256
#define BT 64
#define NTH 512
#define T_STEPS 9

typedef __attribute__((ext_vector_type(8))) short short8;
typedef __attribute__((ext_vector_type(8))) _Float16 half8;
typedef __attribute__((ext_vector_type(2))) _Float16 half2v;
typedef __attribute__((ext_vector_type(4))) float f32x4;

#if __has_builtin(__builtin_amdgcn_exp2f)
#define EXP2(x) __builtin_amdgcn_exp2f(x)
#else
#define EXP2(x) exp2f(x)
#endif

// prologue-only tanh (exp-based)
__device__ __forceinline__ float tanh_plain(float x) {
  float e = __expf(2.0f * x);
  float r = __builtin_amdgcn_rcpf(e + 1.0f);
  return __builtin_fmaf(-2.0f, r, 1.0f);
}
__device__ __forceinline__ f32x4 mfma16h(half8 a, half8 b, f32x4 c) {
  return __builtin_amdgcn_mfma_f32_16x16x32_f16(a, b, c, 0, 0, 0);
}
#if __has_builtin(__builtin_amdgcn_cvt_pkrtz)
__device__ __forceinline__ unsigned pack2h(float a, float b) {
  return __builtin_bit_cast(unsigned, __builtin_amdgcn_cvt_pkrtz(a, b));
}
#else
__device__ __forceinline__ unsigned pack2h(float a, float b) {
  unsigned short ua = __builtin_bit_cast(unsigned short, (_Float16)a);
  unsigned short ub = __builtin_bit_cast(unsigned short, (_Float16)b);
  return (unsigned)ua | ((unsigned)ub << 16);
}
#endif

// Pack B1/B2 into fp16 A-fragments, stream-ordered: chunk s = w*8+kk, then Mt.
// Lane l of tile (Mt,kk) holds A[r=Mt*16+(l&15)][k=kk*32+(l>>4)*8+i], i=0..7.
// Offset: ((s*16 + Mt)*512) + l*8  -> chunk stride is 8192 halves (16 KB).
__global__ __launch_bounds__(64) void prep_w(const float* __restrict__ B1,
                                             const float* __restrict__ B2,
                                             _Float16* __restrict__ Wh) {
  const int blk = blockIdx.x;
  const int w = blk >> 7, rem = blk & 127;
  const int Mt = rem >> 3, kk = rem & 7;
  const int l = threadIdx.x, c = l & 15, g = l >> 4;
  const float* src = (w == 0 ? B1 : B2 + (size_t)(w - 1) * RD * RD)
                     + (size_t)(Mt * 16 + c) * RD + kk * 32 + g * 8;
  _Float16* d = Wh + (size_t)(((w * 8 + kk) * 16 + Mt) * 512) + l * 8;
  #pragma unroll
  for (int i = 0; i < 8; ++i) d[i] = (_Float16)src[i];
}

// One w-slot: 8 kk-chunks of MFMA into acc; optionally interleave the
// 32-element epilogue of the PREVIOUS w (pacc) 4-elements-per-kk.
template <bool DOEPI>
__device__ __forceinline__ void slot_run(
    f32x4 (&acc)[2][4], f32x4 (&pacc)[2][4], half8 (&Ab)[4][2],
    const half8 (&Breg)[8][4], const _Float16*& pPre,
    float (&mast)[2][4][4], float sA2p, const float (&coefp)[4],
    const float (&lep)[8]) {
  const f32x4 zero = {0.f, 0.f, 0.f, 0.f};
  #pragma unroll
  for (int mt = 0; mt < 2; ++mt)
    #pragma unroll
    for (int nt = 0; nt < 4; ++nt) acc[mt][nt] = zero;

  #pragma unroll
  for (int kk = 0; kk < 8; ++kk) {
    const int cur = kk & 3;
    #pragma unroll
    for (int nt = 0; nt < 4; ++nt) {
      acc[0][nt] = mfma16h(Ab[cur][0], Breg[kk][nt], acc[0][nt]);
      acc[1][nt] = mfma16h(Ab[cur][1], Breg[kk][nt], acc[1][nt]);
    }
    if (DOEPI) {
      #pragma unroll
      for (int e = kk * 4; e < kk * 4 + 4; ++e) {
        const int mt_ = e >> 4, nt_ = (e >> 2) & 3, i_ = e & 3;
        const float z = __builtin_fmaf(sA2p, pacc[mt_][nt_][i_], lep[mt_ * 4 + i_]);
        const float r = __builtin_amdgcn_rcpf(EXP2(z) + 1.0f);
        const float th = __builtin_fmaf(-2.0f, r, 1.0f);
        mast[mt_][nt_][i_] = __builtin_fmaf(coefp[nt_], th, mast[mt_][nt_][i_]);
      }
    }
    Ab[cur][0] = *(const half8*)(pPre);
    Ab[cur][1] = *(const half8*)(pPre + 512);
    pPre += 8192;
  }
}

__global__ __launch_bounds__(NTH, 2) void sde_main(
    const float* __restrict__ V, const float* __restrict__ inc,
    const float* __restrict__ W1, const float* __restrict__ b1,
    const float* __restrict__ W2, const float* __restrict__ b2,
    const float* __restrict__ rho1p, const float* __restrict__ rho2p,
    const float* __restrict__ rho3p, const float* __restrict__ rho4p,
    const float* __restrict__ lam1, const float* __restrict__ lam2,
    const float* __restrict__ Wro, const float* __restrict__ bro,
    const _Float16* __restrict__ Wh, float* __restrict__ out) {
  // Exchange buffer: R_t fp16 B-fragments; slot (kk,gq,b) at (kk*4+gq)*64+b,
  // element i holds R[k=kk*32+gq*8+i][b].
  __shared__ short8 Bex[2048];                  // 32 KB (aliases W2s)
  __shared__ float dW_s[T_STEPS * 8 * BT];      // 18 KB
  __shared__ float lam_e[9 * RD];               // 9 KB: 2*log2e*rB*lam
  __shared__ float ro_part[8 * BT];             // 2 KB

  const int tid = threadIdx.x;
  const int wv = tid >> 6, l = tid & 63, c = l & 15, g = l >> 4;
  // wave wv in [0,8): rows [32wv, 32wv+32) (Mt = 2wv, 2wv+1), all 64 batches.
  const int b_base = blockIdx.x * BT;
  const float LOG2E = 1.4426950408889634f;
  const float sa1_2 = 2.0f * LOG2E * rho1p[0];
  const float sa3_2 = 2.0f * LOG2E * rho3p[0];

  float* W2s  = (float*)Bex;   // 32 KB, prologue only
  float* actT = lam_e;         // 8 KB of 9 KB, prologue only

  // ---- phase A: stage W2, activations, dW ----
  {
    const float4* s = (const float4*)W2;
    float4* d = (float4*)W2s;
    #pragma unroll
    for (int j = 0; j < 4; ++j) d[j * NTH + tid] = s[j * NTH + tid];
  }
  {
    const int b = tid & 63, h0 = (tid >> 6) << 2;
    const float* Vb = V + (size_t)(b_base + b) * 16;
    float v[16];
    #pragma unroll
    for (int k = 0; k < 16; ++k) v[k] = Vb[k];
    #pragma unroll
    for (int i = 0; i < 4; ++i) {
      const int h = h0 + i;
      float s = b1[h];
      #pragma unroll
      for (int k = 0; k < 16; ++k) s += v[k] * W1[h * 16 + k];
      actT[h * 64 + b] = tanh_plain(s);
    }
  }
  {
    const int b = tid >> 3, m = tid & 7;
    const float* ib = inc + (size_t)(b_base + b) * 80 + m;
    dW_s[m * BT + b] = ib[0] + ib[8];
    #pragma unroll
    for (int t = 1; t < 9; ++t) dW_s[(t * 8 + m) * BT + b] = ib[(t + 1) * 8];
  }
  __syncthreads();

  // ---- phase B: R0 in C/D layout: rows 32wv+16mt+4g+i, cols nt*16+c ----
  float mast[2][4][4];
  #pragma unroll
  for (int mt = 0; mt < 2; ++mt)
    #pragma unroll
    for (int i = 0; i < 4; ++i) {
      const float bb = b2[32 * wv + 16 * mt + 4 * g + i];
      #pragma unroll
      for (int nt = 0; nt < 4; ++nt) mast[mt][nt][i] = bb;
    }
  #pragma unroll 4
  for (int h = 0; h < 32; ++h) {
    float a[4];
    #pragma unroll
    for (int nt = 0; nt < 4; ++nt) a[nt] = actT[h * 64 + nt * 16 + c];
    #pragma unroll
    for (int mt = 0; mt < 2; ++mt)
      #pragma unroll
      for (int i = 0; i < 4; ++i) {
        const float w2v = W2s[(32 * wv + 16 * mt + 4 * g + i) * 32 + h];
        #pragma unroll
        for (int nt = 0; nt < 4; ++nt) mast[mt][nt][i] += w2v * a[nt];
      }
  }

  auto partials = [&](int t) {
    float s[4] = {0.f, 0.f, 0.f, 0.f};
    #pragma unroll
    for (int mt = 0; mt < 2; ++mt)
      #pragma unroll
      for (int i = 0; i < 4; ++i) {
        const float wr = Wro[t * RD + 32 * wv + 16 * mt + 4 * g + i];
        #pragma unroll
        for (int nt = 0; nt < 4; ++nt) s[nt] += wr * mast[mt][nt][i];
      }
    #pragma unroll
    for (int nt = 0; nt < 4; ++nt) {
      s[nt] += __shfl_xor(s[nt], 16);
      s[nt] += __shfl_xor(s[nt], 32);
    }
    if (g == 0) {
      #pragma unroll
      for (int nt = 0; nt < 4; ++nt) ro_part[wv * BT + nt * 16 + c] = s[nt];
    }
  };

  // master fp32 -> fp16 exchange fragments.  Row 32wv+16mt+4g+i is k-chunk
  // kk=wv, gq = 2mt+(g>>1), in-slot element 4*(g&1)+i.
  auto write_ex = [&]() {
    #pragma unroll
    for (int mt = 0; mt < 2; ++mt) {
      const int gq = 2 * mt + (g >> 1);
      const int hb = g & 1;
      #pragma unroll
      for (int nt = 0; nt < 4; ++nt) {
        const int slot = (wv * 4 + gq) * 64 + nt * 16 + c;
        uint2 pk;
        pk.x = pack2h(mast[mt][nt][0], mast[mt][nt][1]);
        pk.y = pack2h(mast[mt][nt][2], mast[mt][nt][3]);
        *((uint2*)((char*)&Bex[slot] + hb * 8)) = pk;
      }
    }
  };

  partials(0);
  __syncthreads();   // W2s/actT reads done; ro_part(0) visible
  {
    const float rb2 = 2.0f * LOG2E * rho2p[0], rb4 = 2.0f * LOG2E * rho4p[0];
    for (int j = tid; j < 2304; j += NTH)
      lam_e[j] = (j < 256) ? rb2 * lam1[j] : rb4 * lam2[j - 256];
  }
  if (tid < BT) {
    float x = bro[0];
    #pragma unroll
    for (int q = 0; q < 8; ++q) x += ro_part[q * BT + tid];
    out[(size_t)(b_base + tid) * 10] = x;
  }
  write_ex();
  __syncthreads();   // lam_e + exchange(R0) visible

  const _Float16* pA0 = Wh + 2 * wv * 512 + l * 8;  // wave's Mt pair, chunk 0
  const float ones[4] = {1.0f, 1.0f, 1.0f, 1.0f};

  for (int t = 0; t < T_STEPS; ++t) {
    // B-fragments for the whole t-step (all 9 w reuse them)
    half8 Breg[8][4];
    #pragma unroll
    for (int kk = 0; kk < 8; ++kk)
      #pragma unroll
      for (int nt = 0; nt < 4; ++nt)
        Breg[kk][nt] = __builtin_bit_cast(
            half8, Bex[(kk * 4 + g) * 64 + nt * 16 + c]);

    // prime 4-deep A prefetch (chunks 0..3)
    half8 Ab[4][2];
    const _Float16* pPre = pA0;
    #pragma unroll
    for (int d = 0; d < 4; ++d) {
      Ab[d][0] = *(const half8*)(pPre);
      Ab[d][1] = *(const half8*)(pPre + 512);
      pPre += 8192;
    }

    f32x4 accA[2][4], accB[2][4];
    float lepz[8];
    #pragma unroll
    for (int q = 0; q < 8; ++q) lepz[q] = 0.f;

    // w = 0 -> accA, no epilogue interleave
    slot_run<false>(accA, accB, Ab, Breg, pPre, mast, 0.f, ones, lepz);

    // pairs: w=2p+1 -> accB (epilogue of w=2p on accA),
    //        w=2p+2 -> accA (epilogue of w=2p+1 on accB)
    #pragma unroll 1
    for (int p = 0; p < 4; ++p) {
      {
        const int pv = 2 * p;          // previous w being epilogued
        float coefp[4], lep[8];
        float sA2p;
        if (pv == 0) {
          sA2p = sa1_2;
          #pragma unroll
          for (int nt = 0; nt < 4; ++nt) coefp[nt] = 1.0f;
        } else {
          sA2p = sa3_2;
          #pragma unroll
          for (int nt = 0; nt < 4; ++nt)
            coefp[nt] = dW_s[(t * 8 + pv - 1) * BT + nt * 16 + c];
        }
        const float4 l0 = *(const float4*)&lam_e[pv * RD + 32 * wv + 4 * g];
        const float4 l1 = *(const float4*)&lam_e[pv * RD + 32 * wv + 16 + 4 * g];
        lep[0] = l0.x; lep[1] = l0.y; lep[2] = l0.z; lep[3] = l0.w;
        lep[4] = l1.x; lep[5] = l1.y; lep[6] = l1.z; lep[7] = l1.w;
        slot_run<true>(accB, accA, Ab, Breg, pPre, mast, sA2p, coefp, lep);
      }
      {
        const int pv = 2 * p + 1;
        float coefp[4], lep[8];
        #pragma unroll
        for (int nt = 0; nt < 4; ++nt)
          coefp[nt] = dW_s[(t * 8 + pv - 1) * BT + nt * 16 + c];
        const float4 l0 = *(const float4*)&lam_e[pv * RD + 32 * wv + 4 * g];
        const float4 l1 = *(const float4*)&lam_e[pv * RD + 32 * wv + 16 + 4 * g];
        lep[0] = l0.x; lep[1] = l0.y; lep[2] = l0.z; lep[3] = l0.w;
        lep[4] = l1.x; lep[5] = l1.y; lep[6] = l1.z; lep[7] = l1.w;
        slot_run<true>(accA, accB, Ab, Breg, pPre, mast, sa3_2, coefp, lep);
      }
    }

    // final epilogue: w = 8 (accA)
    {
      float coefp[4], lep[8];
      #pragma unroll
      for (int nt = 0; nt < 4; ++nt)
        coefp[nt] = dW_s[(t * 8 + 7) * BT + nt * 16 + c];
      const float4 l0 = *(const float4*)&lam_e[8 * RD + 32 * wv + 4 * g];
      const float4 l1 = *(const float4*)&lam_e[8 * RD + 32 * wv + 16 + 4 * g];
      lep[0] = l0.x; lep[1] = l0.y; lep[2] = l0.z; lep[3] = l0.w;
      lep[4] = l1.x; lep[5] = l1.y; lep[6] = l1.z; lep[7] = l1.w;
      #pragma unroll
      for (int e = 0; e < 32; ++e) {
        const int mt_ = e >> 4, nt_ = (e >> 2) & 3, i_ = e & 3;
        const float z = __builtin_fmaf(sa3_2, accA[mt_][nt_][i_], lep[mt_ * 4 + i_]);
        const float r = __builtin_amdgcn_rcpf(EXP2(z) + 1.0f);
        const float th = __builtin_fmaf(-2.0f, r, 1.0f);
        mast[mt_][nt_][i_] = __builtin_fmaf(coefp[nt_], th, mast[mt_][nt_][i_]);
      }
    }

    partials(t + 1);
    __syncthreads();            // Bex reads (Breg) + ro_part writes complete
    if (tid < BT) {
      float x = bro[t + 1];
      #pragma unroll
      for (int q = 0; q < 8; ++q) x += ro_part[q * BT + tid];
      out[(size_t)(b_base + tid) * 10 + (t + 1)] = x;
    }
    if (t < T_STEPS - 1) write_ex();
    __syncthreads();            // exchange(R_{t+1}) visible
  }
}

extern "C" void kernel_launch(void* const* d_in, const int* in_sizes, int n_in,
                              void* d_out, int out_size, void* d_ws, size_t ws_size,
                              hipStream_t stream) {
  const float* V    = (const float*)d_in[0];
  const float* inc  = (const float*)d_in[1];
  const float* W1   = (const float*)d_in[2];
  const float* b1   = (const float*)d_in[3];
  const float* W2   = (const float*)d_in[4];
  const float* b2   = (const float*)d_in[5];
  const float* rho1 = (const float*)d_in[6];
  const float* rho2 = (const float*)d_in[7];
  const float* rho3 = (const float*)d_in[8];
  const float* rho4 = (const float*)d_in[9];
  const float* B1   = (const float*)d_in[10];
  const float* B2   = (const float*)d_in[11];
  const float* lam1 = (const float*)d_in[12];
  const float* lam2 = (const float*)d_in[13];
  const float* Wro  = (const float*)d_in[14];
  const float* bro  = (const float*)d_in[15];
  float* out = (float*)d_out;

  _Float16* Wh = (_Float16*)d_ws;   // 72 chunks used + 4 over-read pad, < ws

  const int B = in_sizes[0] / 16;

  prep_w<<<9 * 16 * 8, 64, 0, stream>>>(B1, B2, Wh);
  sde_main<<<B / BT, NTH, 0, stream>>>(V, inc, W1, b1, W2, b2,
                                       rho1, rho2, rho3, rho4,
                                       lam1, lam2, Wro, bro, Wh, out);
}

// Round 9
// 331.767 us; speedup vs baseline: 1.7004x; 1.7004x over previous
//
#include <hip/hip_runtime.h>

#define RD 256
#define BT 64
#define NTH 512
#define T_STEPS 9

typedef __attribute__((ext_vector_type(8))) short short8;
typedef __attribute__((ext_vector_type(8))) _Float16 half8;
typedef __attribute__((ext_vector_type(4))) float f32x4;

#if __has_builtin(__builtin_amdgcn_exp2f)
#define EXP2(x) __builtin_amdgcn_exp2f(x)
#else
#define EXP2(x) exp2f(x)
#endif

__device__ __forceinline__ float tanh_plain(float x) {
  float e = __expf(2.0f * x);
  float r = __builtin_amdgcn_rcpf(e + 1.0f);
  return __builtin_fmaf(-2.0f, r, 1.0f);
}
__device__ __forceinline__ f32x4 mfma16h(half8 a, half8 b, f32x4 c) {
  return __builtin_amdgcn_mfma_f32_16x16x32_f16(a, b, c, 0, 0, 0);
}
#if __has_builtin(__builtin_amdgcn_cvt_pkrtz)
__device__ __forceinline__ unsigned pack2h(float a, float b) {
  return __builtin_bit_cast(unsigned, __builtin_amdgcn_cvt_pkrtz(a, b));
}
#else
__device__ __forceinline__ unsigned pack2h(float a, float b) {
  unsigned short ua = __builtin_bit_cast(unsigned short, (_Float16)a);
  unsigned short ub = __builtin_bit_cast(unsigned short, (_Float16)b);
  return (unsigned)ua | ((unsigned)ub << 16);
}
#endif

// Pack B1/B2 into fp16 A-fragments, stream-ordered: chunk s = w*8+kk, then Mt.
// Lane l of tile (Mt,kk) holds A[r=Mt*16+(l&15)][k=kk*32+(l>>4)*8+i], i=0..7.
// Offset: ((s*16 + Mt)*512) + l*8.  Per (w,h) pass: base + kk*8192 (+h*512).
__global__ __launch_bounds__(64) void prep_w(const float* __restrict__ B1,
                                             const float* __restrict__ B2,
                                             _Float16* __restrict__ Wh) {
  const int blk = blockIdx.x;
  const int w = blk >> 7, rem = blk & 127;
  const int Mt = rem >> 3, kk = rem & 7;
  const int l = threadIdx.x, c = l & 15, g = l >> 4;
  const float* src = (w == 0 ? B1 : B2 + (size_t)(w - 1) * RD * RD)
                     + (size_t)(Mt * 16 + c) * RD + kk * 32 + g * 8;
  _Float16* d = Wh + (size_t)(((w * 8 + kk) * 16 + Mt) * 512) + l * 8;
  #pragma unroll
  for (int i = 0; i < 8; ++i) d[i] = (_Float16)src[i];
}

// One half-slot: 8 kk, 4 nt MFMAs into acc (Mt = 2wv+H), with the 16-elem
// epilogue of the PREVIOUS half-slot (pacc -> mast[MTP]) interleaved 2/kk,
// and lookahead-3 rolling A prefetch (Ab[4], all offsets compile-time).
template <int H, bool DOEPI, int MTP>
__device__ __forceinline__ void run_slot(
    f32x4 (&acc)[4], const f32x4 (&pacc)[4], half8 (&Ab)[4],
    const half8 (&Breg)[8][4], const _Float16* pw,
    float (&mast)[2][4][4], float sA2, const float (&coef)[4],
    const float (&lep)[4]) {
  const f32x4 zero = {0.f, 0.f, 0.f, 0.f};
  #pragma unroll
  for (int kk = 0; kk < 8; ++kk) {
    const half8 a = Ab[kk & 3];
    #pragma unroll
    for (int nt = 0; nt < 4; ++nt)
      acc[nt] = mfma16h(a, Breg[kk][nt], (kk == 0) ? zero : acc[nt]);
    if (DOEPI) {
      const int nt_ = kk >> 1, i0 = (2 * kk) & 3, i1 = (2 * kk + 1) & 3;
      const float z0 = __builtin_fmaf(sA2, pacc[nt_][i0], lep[i0]);
      const float z1 = __builtin_fmaf(sA2, pacc[nt_][i1], lep[i1]);
      const float r0 = __builtin_amdgcn_rcpf(EXP2(z0) + 1.0f);
      const float r1 = __builtin_amdgcn_rcpf(EXP2(z1) + 1.0f);
      const float t0 = __builtin_fmaf(-2.0f, r0, 1.0f);
      const float t1 = __builtin_fmaf(-2.0f, r1, 1.0f);
      mast[MTP][nt_][i0] = __builtin_fmaf(coef[nt_], t0, mast[MTP][nt_][i0]);
      mast[MTP][nt_][i1] = __builtin_fmaf(coef[nt_], t1, mast[MTP][nt_][i1]);
    }
    // prefetch stream position kk+3 into Ab[(kk+3)&3]
    const int off = (kk <= 4) ? ((kk + 3) * 8192 + H * 512)
                              : (H == 0 ? (kk - 5) * 8192 + 512
                                        : 65536 + (kk - 5) * 8192);
    Ab[(kk + 3) & 3] = *(const half8*)(pw + off);
  }
}

__global__ __launch_bounds__(NTH, 2) void sde_main(
    const float* __restrict__ V, const float* __restrict__ inc,
    const float* __restrict__ W1, const float* __restrict__ b1,
    const float* __restrict__ W2, const float* __restrict__ b2,
    const float* __restrict__ rho1p, const float* __restrict__ rho2p,
    const float* __restrict__ rho3p, const float* __restrict__ rho4p,
    const float* __restrict__ lam1, const float* __restrict__ lam2,
    const float* __restrict__ Wro, const float* __restrict__ bro,
    const _Float16* __restrict__ Wh, float* __restrict__ out) {
  __shared__ short8 Bex[2048];                  // 32 KB (aliases W2s)
  __shared__ float dW_s[T_STEPS * 8 * BT];      // 18 KB
  __shared__ float lam_e[9 * RD];               // 9 KB: 2*log2e*rB*lam
  __shared__ float ro_part[8 * BT];             // 2 KB

  const int tid = threadIdx.x;
  const int wv = tid >> 6, l = tid & 63, c = l & 15, g = l >> 4;
  const int b_base = blockIdx.x * BT;
  const float LOG2E = 1.4426950408889634f;
  const float sa1_2 = 2.0f * LOG2E * rho1p[0];
  const float sa3_2 = 2.0f * LOG2E * rho3p[0];

  float* W2s  = (float*)Bex;   // prologue only
  float* actT = lam_e;         // prologue only

  // ---- phase A ----
  {
    const float4* s = (const float4*)W2;
    float4* d = (float4*)W2s;
    #pragma unroll
    for (int j = 0; j < 4; ++j) d[j * NTH + tid] = s[j * NTH + tid];
  }
  {
    const int b = tid & 63, h0 = (tid >> 6) << 2;
    const float* Vb = V + (size_t)(b_base + b) * 16;
    float v[16];
    #pragma unroll
    for (int k = 0; k < 16; ++k) v[k] = Vb[k];
    #pragma unroll
    for (int i = 0; i < 4; ++i) {
      const int h = h0 + i;
      float s = b1[h];
      #pragma unroll
      for (int k = 0; k < 16; ++k) s += v[k] * W1[h * 16 + k];
      actT[h * 64 + b] = tanh_plain(s);
    }
  }
  {
    const int b = tid >> 3, m = tid & 7;
    const float* ib = inc + (size_t)(b_base + b) * 80 + m;
    dW_s[m * BT + b] = ib[0] + ib[8];
    #pragma unroll
    for (int t = 1; t < 9; ++t) dW_s[(t * 8 + m) * BT + b] = ib[(t + 1) * 8];
  }
  __syncthreads();

  // ---- phase B: R0 ----
  float mast[2][4][4];
  #pragma unroll
  for (int mt = 0; mt < 2; ++mt)
    #pragma unroll
    for (int i = 0; i < 4; ++i) {
      const float bb = b2[32 * wv + 16 * mt + 4 * g + i];
      #pragma unroll
      for (int nt = 0; nt < 4; ++nt) mast[mt][nt][i] = bb;
    }
  #pragma unroll 4
  for (int h = 0; h < 32; ++h) {
    float a[4];
    #pragma unroll
    for (int nt = 0; nt < 4; ++nt) a[nt] = actT[h * 64 + nt * 16 + c];
    #pragma unroll
    for (int mt = 0; mt < 2; ++mt)
      #pragma unroll
      for (int i = 0; i < 4; ++i) {
        const float w2v = W2s[(32 * wv + 16 * mt + 4 * g + i) * 32 + h];
        #pragma unroll
        for (int nt = 0; nt < 4; ++nt) mast[mt][nt][i] += w2v * a[nt];
      }
  }

  auto partials = [&](int t) {
    float s[4] = {0.f, 0.f, 0.f, 0.f};
    #pragma unroll
    for (int mt = 0; mt < 2; ++mt)
      #pragma unroll
      for (int i = 0; i < 4; ++i) {
        const float wr = Wro[t * RD + 32 * wv + 16 * mt + 4 * g + i];
        #pragma unroll
        for (int nt = 0; nt < 4; ++nt) s[nt] += wr * mast[mt][nt][i];
      }
    #pragma unroll
    for (int nt = 0; nt < 4; ++nt) {
      s[nt] += __shfl_xor(s[nt], 16);
      s[nt] += __shfl_xor(s[nt], 32);
    }
    if (g == 0) {
      #pragma unroll
      for (int nt = 0; nt < 4; ++nt) ro_part[wv * BT + nt * 16 + c] = s[nt];
    }
  };

  auto write_ex = [&]() {
    #pragma unroll
    for (int mt = 0; mt < 2; ++mt) {
      const int gq = 2 * mt + (g >> 1);
      const int hb = g & 1;
      #pragma unroll
      for (int nt = 0; nt < 4; ++nt) {
        const int slot = (wv * 4 + gq) * 64 + nt * 16 + c;
        uint2 pk;
        pk.x = pack2h(mast[mt][nt][0], mast[mt][nt][1]);
        pk.y = pack2h(mast[mt][nt][2], mast[mt][nt][3]);
        *((uint2*)((char*)&Bex[slot] + hb * 8)) = pk;
      }
    }
  };

  partials(0);
  __syncthreads();
  {
    const float rb2 = 2.0f * LOG2E * rho2p[0], rb4 = 2.0f * LOG2E * rho4p[0];
    for (int j = tid; j < 2304; j += NTH)
      lam_e[j] = (j < 256) ? rb2 * lam1[j] : rb4 * lam2[j - 256];
  }
  if (tid < BT) {
    float x = bro[0];
    #pragma unroll
    for (int q = 0; q < 8; ++q) x += ro_part[q * BT + tid];
    out[(size_t)(b_base + tid) * 10] = x;
  }
  write_ex();
  __syncthreads();

  const _Float16* pA0 = Wh + 2 * wv * 512 + l * 8;
  const float ones4[4] = {1.f, 1.f, 1.f, 1.f};
  const float lep0[4] = {0.f, 0.f, 0.f, 0.f};

  for (int t = 0; t < T_STEPS; ++t) {
    half8 Breg[8][4];
    #pragma unroll
    for (int kk = 0; kk < 8; ++kk)
      #pragma unroll
      for (int nt = 0; nt < 4; ++nt)
        Breg[kk][nt] = __builtin_bit_cast(
            half8, Bex[(kk * 4 + g) * 64 + nt * 16 + c]);

    half8 Ab[4];
    Ab[0] = *(const half8*)(pA0);
    Ab[1] = *(const half8*)(pA0 + 8192);
    Ab[2] = *(const half8*)(pA0 + 16384);
    const _Float16* pw = pA0;

    f32x4 aX[4], aY[4];

    // slot (0,0) -> aX, no epilogue
    run_slot<0, false, 0>(aX, aY, Ab, Breg, pw, mast, 0.f, ones4, lep0);
    // slot (0,1) -> aY, epilogue of (0,0): drift (coef=1, sa1)
    {
      float lepA[4];
      const float4 lv = *(const float4*)&lam_e[32 * wv + 4 * g];
      lepA[0] = lv.x; lepA[1] = lv.y; lepA[2] = lv.z; lepA[3] = lv.w;
      run_slot<1, true, 0>(aY, aX, Ab, Breg, pw, mast, sa1_2, ones4, lepA);
    }

    #pragma unroll 1
    for (int w = 1; w < 9; ++w) {
      pw += 65536;
      // epilogue of (w-1, h=1) during slot (w,0)
      {
        const float sA2a = (w == 1) ? sa1_2 : sa3_2;
        const int ia = (w == 1) ? 0 : (t * 8 + w - 2);
        float coefA[4], lepB[4];
        #pragma unroll
        for (int nt = 0; nt < 4; ++nt) {
          const float dv = dW_s[ia * BT + nt * 16 + c];
          coefA[nt] = (w == 1) ? 1.0f : dv;
        }
        const float4 lv = *(const float4*)&lam_e[(w - 1) * RD + 32 * wv + 16 + 4 * g];
        lepB[0] = lv.x; lepB[1] = lv.y; lepB[2] = lv.z; lepB[3] = lv.w;
        run_slot<0, true, 1>(aX, aY, Ab, Breg, pw, mast, sA2a, coefA, lepB);
      }
      // epilogue of (w, h=0) during slot (w,1)
      {
        float coefB[4], lepC[4];
        #pragma unroll
        for (int nt = 0; nt < 4; ++nt)
          coefB[nt] = dW_s[(t * 8 + w - 1) * BT + nt * 16 + c];
        const float4 lv = *(const float4*)&lam_e[w * RD + 32 * wv + 4 * g];
        lepC[0] = lv.x; lepC[1] = lv.y; lepC[2] = lv.z; lepC[3] = lv.w;
        run_slot<1, true, 0>(aY, aX, Ab, Breg, pw, mast, sa3_2, coefB, lepC);
      }
    }

    // final epilogue: slot (8,1) -> mast[1]
    {
      float coefF[4], lepF[4];
      #pragma unroll
      for (int nt = 0; nt < 4; ++nt)
        coefF[nt] = dW_s[(t * 8 + 7) * BT + nt * 16 + c];
      const float4 lv = *(const float4*)&lam_e[8 * RD + 32 * wv + 16 + 4 * g];
      lepF[0] = lv.x; lepF[1] = lv.y; lepF[2] = lv.z; lepF[3] = lv.w;
      #pragma unroll
      for (int kk = 0; kk < 8; ++kk) {
        const int nt_ = kk >> 1, i0 = (2 * kk) & 3, i1 = (2 * kk + 1) & 3;
        const float z0 = __builtin_fmaf(sa3_2, aY[nt_][i0], lepF[i0]);
        const float z1 = __builtin_fmaf(sa3_2, aY[nt_][i1], lepF[i1]);
        const float r0 = __builtin_amdgcn_rcpf(EXP2(z0) + 1.0f);
        const float r1 = __builtin_amdgcn_rcpf(EXP2(z1) + 1.0f);
        const float t0 = __builtin_fmaf(-2.0f, r0, 1.0f);
        const float t1 = __builtin_fmaf(-2.0f, r1, 1.0f);
        mast[1][nt_][i0] = __builtin_fmaf(coefF[nt_], t0, mast[1][nt_][i0]);
        mast[1][nt_][i1] = __builtin_fmaf(coefF[nt_], t1, mast[1][nt_][i1]);
      }
    }

    partials(t + 1);
    __syncthreads();
    if (tid < BT) {
      float x = bro[t + 1];
      #pragma unroll
      for (int q = 0; q < 8; ++q) x += ro_part[q * BT + tid];
      out[(size_t)(b_base + tid) * 10 + (t + 1)] = x;
    }
    if (t < T_STEPS - 1) write_ex();
    __syncthreads();
  }
}

extern "C" void kernel_launch(void* const* d_in, const int* in_sizes, int n_in,
                              void* d_out, int out_size, void* d_ws, size_t ws_size,
                              hipStream_t stream) {
  const float* V    = (const float*)d_in[0];
  const float* inc  = (const float*)d_in[1];
  const float* W1   = (const float*)d_in[2];
  const float* b1   = (const float*)d_in[3];
  const float* W2   = (const float*)d_in[4];
  const float* b2   = (const float*)d_in[5];
  const float* rho1 = (const float*)d_in[6];
  const float* rho2 = (const float*)d_in[7];
  const float* rho3 = (const float*)d_in[8];
  const float* rho4 = (const float*)d_in[9];
  const float* B1   = (const float*)d_in[10];
  const float* B2   = (const float*)d_in[11];
  const float* lam1 = (const float*)d_in[12];
  const float* lam2 = (const float*)d_in[13];
  const float* Wro  = (const float*)d_in[14];
  const float* bro  = (const float*)d_in[15];
  float* out = (float*)d_out;

  _Float16* Wh = (_Float16*)d_ws;   // 72 chunks + over-read pad, < ws_size

  const int B = in_sizes[0] / 16;

  prep_w<<<9 * 16 * 8, 64, 0, stream>>>(B1, B2, Wh);
  sde_main<<<B / BT, NTH, 0, stream>>>(V, inc, W1, b1, W2, b2,
                                       rho1, rho2, rho3, rho4,
                                       lam1, lam2, Wro, bro, Wh, out);
}